// Round 1
// baseline (416.848 us; speedup 1.0000x reference)
//
#include <hip/hip_runtime.h>
#include <hip/hip_bf16.h>

#define B_ 8
#define L1_ 2048
#define L2_ 2048
#define C_ 320
#define H_ 8
#define D_ 64
#define NREG_ 4
#define INNER_ 512
#define LK_ 2052
#define LKP_ 2112   /* 33*64 padded key length */
#define NKV_TILES 33
#define LOG2E 1.44269504f

typedef __bf16 bf16_t;
typedef __attribute__((ext_vector_type(8))) __bf16 bf16x8;
typedef __attribute__((ext_vector_type(4))) __bf16 bf16x4;
typedef __attribute__((ext_vector_type(4))) float f32x4;

__device__ __forceinline__ f32x4 mfma16(bf16x8 a, bf16x8 b, f32x4 c){
  return __builtin_amdgcn_mfma_f32_16x16x32_bf16(a, b, c, 0, 0, 0);
}

__device__ __forceinline__ void gl_lds16(const char* g, char* l){
  __builtin_amdgcn_global_load_lds(
      (const __attribute__((address_space(1))) unsigned int*)g,
      (__attribute__((address_space(3))) unsigned int*)l, 16, 0, 0);
}

// ---------------- mask dtype detection ----------------
// numpy bool -> 1 byte/elem (values 0/1, iid) ; int32 -> bytes at pos%4!=0 are 0.
__global__ void k_detect(const unsigned char* mask, int* flag){
  if (threadIdx.x == 0 && blockIdx.x == 0){
    int f = 1; // assume int32
    for (int i = 0; i < 256; i++){
      if ((i & 3) != 0 && mask[i] != 0){ f = 0; break; } // byte-sized (bool)
    }
    *flag = f;
  }
}

// ---------------- weight transpose fp32[K][N] -> bf16[N][K] ----------------
__global__ void k_transpose(const float* __restrict__ W, bf16_t* __restrict__ Wt,
                            int K, int N){
  __shared__ float t[32][33];
  int n0 = blockIdx.x * 32, k0 = blockIdx.y * 32;
  int tx = threadIdx.x & 31, ty = threadIdx.x >> 5;
  for (int r = ty; r < 32; r += 8) t[r][tx] = W[(long)(k0 + r) * N + n0 + tx];
  __syncthreads();
  for (int r = ty; r < 32; r += 8) Wt[(long)(n0 + r) * K + k0 + tx] = (bf16_t)t[tx][r];
}

// ---------------- mask -> packed bits over padded kv domain [0,2112) ----------------
__global__ void k_maskcompact(const void* __restrict__ maskv, const int* __restrict__ flag,
                              unsigned int* __restrict__ maskp){
  int row = blockIdx.x * 4 + (threadIdx.x >> 6);   // 0..16383 = b*2048+q
  int lane = threadIdx.x & 63;
  const unsigned char* mb = (const unsigned char*)maskv;
  const int* mi = (const int*)maskv;
  int isInt = *flag;
  long base = (long)row * L2_;
  unsigned int* orow = maskp + (long)row * 66;
  for (int s = 0; s < 33; s++){
    int kv = s * 64 + lane;
    int vis = 0;
    if (kv < NREG_) vis = 1;
    else if (kv < LK_){
      long idx = base + (kv - NREG_);
      vis = isInt ? (mi[idx] != 0) : (mb[idx] != 0);
    }
    unsigned long long bal = __ballot(vis);
    if (lane == 0)      orow[2*s]   = (unsigned int)bal;
    else if (lane == 1) orow[2*s+1] = (unsigned int)(bal >> 32);
  }
}

// ---------------- projection GEMM: C[m][n] = A[m][0:320] @ W[0:320][n] ----------------
// MODE 0: A = x (M=16384), out Q[((b*8+h)*2048+l1)*64+d]
// MODE 1: A = [reg|context|0] (M=8*2112), out K[((b*8+h)*2112+rr)*64+d]
// MODE 2: same A, out Vt[((b*8+h)*64+d)*2112+rr]  (transposed)
template<int MODE>
__global__ __launch_bounds__(256)
void k_proj(const float* __restrict__ A0, const float* __restrict__ ctx,
            const float* __restrict__ regtok, const bf16_t* __restrict__ Wt,
            bf16_t* __restrict__ out)
{
  __shared__ __align__(16) char As[128*64*2];
  __shared__ __align__(16) char Bs[128*64*2];
  int tid = threadIdx.x;
  int w = tid >> 6, lane = tid & 63, cl = lane & 15, cg = lane >> 4;
  int wr = w >> 1, wc = w & 1;
  int m0 = blockIdx.x * 128, n0 = blockIdx.y * 128;

  f32x4 acc[4][4];
  #pragma unroll
  for (int i = 0; i < 4; i++)
    #pragma unroll
    for (int j = 0; j < 4; j++) acc[i][j] = (f32x4){0,0,0,0};

  for (int kb = 0; kb < 5; ++kb){
    int k0 = kb * 64;
    __syncthreads();
    // stage A (fp32 -> bf16), swizzled [128][64]
    #pragma unroll
    for (int c = 0; c < 8; c++){
      int e = c * 1024 + tid * 4;
      int row = e >> 6, k = e & 63;
      f32x4 v = (f32x4){0,0,0,0};
      if (MODE == 0){
        v = *(const f32x4*)(A0 + (long)(m0 + row) * C_ + k0 + k);
      } else {
        int rg = m0 + row;
        int b = rg / LKP_;
        int rr = rg - b * LKP_;
        const float* src = nullptr;
        if (rr < NREG_)    src = regtok + rr * C_;
        else if (rr < LK_) src = ctx + (long)(b * L1_ + rr - NREG_) * C_;
        if (src) v = *(const f32x4*)(src + k0 + k);
      }
      bf16x4 cv;
      cv[0]=(bf16_t)v[0]; cv[1]=(bf16_t)v[1]; cv[2]=(bf16_t)v[2]; cv[3]=(bf16_t)v[3];
      int off = (row << 7) + ((k << 1) ^ ((row & 7) << 4));
      *(bf16x4*)(As + off) = cv;
    }
    // stage B (Wt bf16 [n][k]) swizzled [128][64]
    #pragma unroll
    for (int c = 0; c < 4; c++){
      int e = c * 2048 + tid * 8;
      int row = e >> 6, k = e & 63;
      bf16x8 v = *(const bf16x8*)(Wt + (long)(n0 + row) * C_ + k0 + k);
      int off = (row << 7) + ((k << 1) ^ ((row & 7) << 4));
      *(bf16x8*)(Bs + off) = v;
    }
    __syncthreads();
    #pragma unroll
    for (int kc = 0; kc < 2; kc++){
      int kk = kc * 32 + cg * 8;
      bf16x8 af[4], bfr[4];
      #pragma unroll
      for (int mt = 0; mt < 4; mt++){
        int row = wr * 64 + mt * 16 + cl;
        af[mt] = *(const bf16x8*)(As + (row << 7) + ((kk << 1) ^ ((row & 7) << 4)));
      }
      #pragma unroll
      for (int nt = 0; nt < 4; nt++){
        int row = wc * 64 + nt * 16 + cl;
        bfr[nt] = *(const bf16x8*)(Bs + (row << 7) + ((kk << 1) ^ ((row & 7) << 4)));
      }
      #pragma unroll
      for (int mt = 0; mt < 4; mt++)
        #pragma unroll
        for (int nt = 0; nt < 4; nt++)
          acc[mt][nt] = mfma16(af[mt], bfr[nt], acc[mt][nt]);
    }
  }

  #pragma unroll
  for (int mt = 0; mt < 4; mt++){
    #pragma unroll
    for (int nt = 0; nt < 4; nt++){
      f32x4 v = acc[mt][nt];
      int row = m0 + wr * 64 + mt * 16 + cg * 4;   // + r
      int col = n0 + wc * 64 + nt * 16 + cl;
      int h = col >> 6, d = col & 63;
      if (MODE == 0){
        int b = row >> 11, l1 = row & 2047;
        bf16_t* p = out + ((long)((b * H_ + h) * L1_ + l1)) * D_ + d;
        #pragma unroll
        for (int r = 0; r < 4; r++) p[r * D_] = (bf16_t)v[r];
      } else if (MODE == 1){
        int b = row / LKP_, rr = row - b * LKP_;
        bf16_t* p = out + ((long)((b * H_ + h) * LKP_ + rr)) * D_ + d;
        #pragma unroll
        for (int r = 0; r < 4; r++) p[r * D_] = (bf16_t)v[r];
      } else {
        int b = row / LKP_, rr = row - b * LKP_;
        bf16x4 cv;
        cv[0]=(bf16_t)v[0]; cv[1]=(bf16_t)v[1]; cv[2]=(bf16_t)v[2]; cv[3]=(bf16_t)v[3];
        *(bf16x4*)(out + ((long)((b * H_ + h) * D_ + d)) * LKP_ + rr) = cv;
      }
    }
  }
}

// ---------------- flash attention ----------------
// block: 64 q rows (4 waves x 16), one (b,h); KV tiles of 64, double-buffered LDS.
__global__ __launch_bounds__(256)
void k_attn(const bf16_t* __restrict__ Q, const bf16_t* __restrict__ K,
            const bf16_t* __restrict__ Vt, const unsigned int* __restrict__ maskp,
            bf16_t* __restrict__ att)
{
  __shared__ __align__(16) char smem[40960]; // 2*(8K K + 8K Vt) + 4*2K P
  int bh = blockIdx.y;
  int b = bh >> 3, h = bh & 7;
  int q0 = blockIdx.x * 64;
  int tid = threadIdx.x;
  int w = tid >> 6, lane = tid & 63, cl = lane & 15, cg = lane >> 4;
  int qw = q0 + w * 16;

  const char* Kg = (const char*)(K + (long)bh * LKP_ * D_);
  const char* Vg = (const char*)(Vt + (long)bh * D_ * LKP_);

  const bf16_t* Qb = Q + ((long)bh * L1_ + qw + cl) * D_;
  bf16x8 qf0 = *(const bf16x8*)(Qb + cg * 8);
  bf16x8 qf1 = *(const bf16x8*)(Qb + 32 + cg * 8);

  f32x4 o[4];
  #pragma unroll
  for (int i = 0; i < 4; i++) o[i] = (f32x4){0,0,0,0};
  float m_r[4] = {-1e30f,-1e30f,-1e30f,-1e30f};
  float s_r[4] = {0,0,0,0};

  char* Pb = smem + 32768 + w * 2048;

  auto stage = [&](int buf, int t){
    char* base = smem + buf * 16384;
    #pragma unroll
    for (int c = 0; c < 2; c++){
      int p = w * 2048 + c * 1024 + lane * 16;
      int row = p >> 7, ir = p & 127;
      int sw = ir ^ ((row & 7) << 4);
      gl_lds16(Kg + (long)(t * 64 + row) * 128 + sw, base + p);
    }
    #pragma unroll
    for (int c = 0; c < 2; c++){
      int p = w * 2048 + c * 1024 + lane * 16;
      int row = p >> 7, ir = p & 127;
      int sw = ir ^ ((row & 7) << 4);
      gl_lds16(Vg + (long)row * (LKP_ * 2) + t * 128 + sw, base + 8192 + p);
    }
  };

  stage(0, 0);
  asm volatile("s_waitcnt vmcnt(0)" ::: "memory");
  __syncthreads();

  for (int t = 0; t < NKV_TILES; ++t){
    int cur = t & 1;
    if (t + 1 < NKV_TILES) stage(cur ^ 1, t + 1);
    const char* Kb = smem + cur * 16384;
    const char* Vb = Kb + 8192;

    // S = Q K^T  (S[q][kv], lane holds q=cg*4+r, kv=kt*16+cl)
    f32x4 s[4];
    #pragma unroll
    for (int kt = 0; kt < 4; kt++){
      int row = kt * 16 + cl;
      bf16x8 kf0 = *(const bf16x8*)(Kb + (row << 7) + ((cg * 16) ^ ((row & 7) << 4)));
      bf16x8 kf1 = *(const bf16x8*)(Kb + (row << 7) + ((64 + cg * 16) ^ ((row & 7) << 4)));
      f32x4 z = (f32x4){0,0,0,0};
      z = mfma16(qf0, kf0, z);
      z = mfma16(qf1, kf1, z);
      s[kt] = z;
    }

    // mask + online softmax
    long mrowbase = ((long)(b * L1_) + qw + cg * 4) * 66 + 2 * t;
    #pragma unroll
    for (int r = 0; r < 4; r++){
      unsigned wd0 = maskp[mrowbase + (long)r * 66];
      unsigned wd1 = maskp[mrowbase + (long)r * 66 + 1];
      float mx = -1e30f;
      float zv[4];
      #pragma unroll
      for (int kt = 0; kt < 4; kt++){
        int kvloc = kt * 16 + cl;
        unsigned wdsel = (kt < 2) ? wd0 : wd1;
        int bit = (wdsel >> (kvloc & 31)) & 1;
        float z = s[kt][r] * 0.125f;
        z = bit ? z : -1e30f;
        zv[kt] = z;
        mx = fmaxf(mx, z);
      }
      mx = fmaxf(mx, __shfl_xor(mx, 1));
      mx = fmaxf(mx, __shfl_xor(mx, 2));
      mx = fmaxf(mx, __shfl_xor(mx, 4));
      mx = fmaxf(mx, __shfl_xor(mx, 8));
      float mnew = fmaxf(m_r[r], mx);
      float f = exp2f((m_r[r] - mnew) * LOG2E);
      m_r[r] = mnew;
      s_r[r] *= f;
      #pragma unroll
      for (int dt = 0; dt < 4; dt++) o[dt][r] *= f;
      #pragma unroll
      for (int kt = 0; kt < 4; kt++){
        float p = exp2f((zv[kt] - mnew) * LOG2E);
        s_r[r] += p;
        int qloc = cg * 4 + r;
        int kv = kt * 16 + cl;
        int off = (qloc << 7) + ((kv << 1) ^ ((qloc & 7) << 4));
        *(bf16_t*)(Pb + off) = (bf16_t)p;
      }
    }

    // O += P @ V   (A-frag from P_lds, B-frag from Vt tile)
    #pragma unroll
    for (int kc = 0; kc < 2; kc++){
      int kk = kc * 32 + cg * 8;
      bf16x8 pa = *(const bf16x8*)(Pb + (cl << 7) + ((kk << 1) ^ ((cl & 7) << 4)));
      #pragma unroll
      for (int dt = 0; dt < 4; dt++){
        int row = dt * 16 + cl;
        bf16x8 vf = *(const bf16x8*)(Vb + (row << 7) + ((kk << 1) ^ ((row & 7) << 4)));
        o[dt] = mfma16(pa, vf, o[dt]);
      }
    }

    asm volatile("s_waitcnt vmcnt(0)" ::: "memory");
    __syncthreads();
  }

  // epilogue: reduce row sums across the 16-lane group, normalize, store
  #pragma unroll
  for (int r = 0; r < 4; r++){
    float tot = s_r[r];
    tot += __shfl_xor(tot, 1);
    tot += __shfl_xor(tot, 2);
    tot += __shfl_xor(tot, 4);
    tot += __shfl_xor(tot, 8);
    float inv = 1.0f / tot;
    int qg = qw + cg * 4 + r;
    bf16_t* op = att + ((long)(b * L1_) + qg) * INNER_ + h * D_;
    #pragma unroll
    for (int dt = 0; dt < 4; dt++)
      op[dt * 16 + cl] = (bf16_t)(o[dt][r] * inv);
  }
}

// ---------------- output GEMM: out[m][c] = att[m][:512] @ Wo + bo ----------------
__global__ __launch_bounds__(256)
void k_out(const bf16_t* __restrict__ A, const bf16_t* __restrict__ Wot,
           const float* __restrict__ bo, float* __restrict__ out)
{
  __shared__ __align__(16) char As[128*64*2];
  __shared__ __align__(16) char Bs[64*64*2];
  int tid = threadIdx.x;
  int w = tid >> 6, lane = tid & 63, cl = lane & 15, cg = lane >> 4;
  int wr = w >> 1, wc = w & 1;
  int m0 = blockIdx.x * 128, n0 = blockIdx.y * 64;

  f32x4 acc[4][2];
  #pragma unroll
  for (int i = 0; i < 4; i++)
    #pragma unroll
    for (int j = 0; j < 2; j++) acc[i][j] = (f32x4){0,0,0,0};

  for (int kb = 0; kb < 8; kb++){
    int k0 = kb * 64;
    __syncthreads();
    #pragma unroll
    for (int c = 0; c < 4; c++){
      int e = c * 2048 + tid * 8;
      int row = e >> 6, k = e & 63;
      bf16x8 v = *(const bf16x8*)(A + (long)(m0 + row) * INNER_ + k0 + k);
      *(bf16x8*)(As + (row << 7) + ((k << 1) ^ ((row & 7) << 4))) = v;
    }
    #pragma unroll
    for (int c = 0; c < 2; c++){
      int e = c * 2048 + tid * 8;
      int row = e >> 6, k = e & 63;
      bf16x8 v = *(const bf16x8*)(Wot + (long)(n0 + row) * INNER_ + k0 + k);
      *(bf16x8*)(Bs + (row << 7) + ((k << 1) ^ ((row & 7) << 4))) = v;
    }
    __syncthreads();
    #pragma unroll
    for (int kc = 0; kc < 2; kc++){
      int kk = kc * 32 + cg * 8;
      bf16x8 af[4], bfr[2];
      #pragma unroll
      for (int mt = 0; mt < 4; mt++){
        int row = wr * 64 + mt * 16 + cl;
        af[mt] = *(const bf16x8*)(As + (row << 7) + ((kk << 1) ^ ((row & 7) << 4)));
      }
      #pragma unroll
      for (int nt = 0; nt < 2; nt++){
        int row = wc * 32 + nt * 16 + cl;
        bfr[nt] = *(const bf16x8*)(Bs + (row << 7) + ((kk << 1) ^ ((row & 7) << 4)));
      }
      #pragma unroll
      for (int mt = 0; mt < 4; mt++)
        #pragma unroll
        for (int nt = 0; nt < 2; nt++)
          acc[mt][nt] = mfma16(af[mt], bfr[nt], acc[mt][nt]);
    }
  }
  #pragma unroll
  for (int mt = 0; mt < 4; mt++)
    #pragma unroll
    for (int nt = 0; nt < 2; nt++){
      int row = m0 + wr * 64 + mt * 16 + cg * 4;
      int col = n0 + wc * 32 + nt * 16 + cl;
      float bias = bo[col];
      #pragma unroll
      for (int r = 0; r < 4; r++)
        out[(long)(row + r) * C_ + col] = acc[mt][nt][r] + bias;
    }
}

extern "C" void kernel_launch(void* const* d_in, const int* in_sizes, int n_in,
                              void* d_out, int out_size, void* d_ws, size_t ws_size,
                              hipStream_t stream)
{
  const float* x    = (const float*)d_in[0];
  const float* ctx  = (const float*)d_in[1];
  const void*  mask = d_in[2];
  const float* Wq   = (const float*)d_in[3];
  const float* Wk   = (const float*)d_in[4];
  const float* Wv   = (const float*)d_in[5];
  const float* Wo   = (const float*)d_in[6];
  const float* bo   = (const float*)d_in[7];
  const float* regt = (const float*)d_in[8];
  float* out = (float*)d_out;

  char* ws = (char*)d_ws;
  size_t off = 0;
  int* flag = (int*)ws;                               off = 256;
  unsigned int* maskp = (unsigned int*)(ws + off);    off += (size_t)16384 * 66 * 4;
  bf16_t* Qw  = (bf16_t*)(ws + off);                  off += (size_t)B_*H_*L1_*D_*2;
  bf16_t* Kw  = (bf16_t*)(ws + off);                  off += (size_t)B_*H_*LKP_*D_*2;
  bf16_t* Vtw = (bf16_t*)(ws + off);                  off += (size_t)B_*H_*D_*LKP_*2;
  bf16_t* Att = (bf16_t*)(ws + off);                  off += (size_t)B_*L1_*INNER_*2;
  bf16_t* Wqt = (bf16_t*)(ws + off);                  off += (size_t)C_*INNER_*2;
  bf16_t* Wkt = (bf16_t*)(ws + off);                  off += (size_t)C_*INNER_*2;
  bf16_t* Wvt = (bf16_t*)(ws + off);                  off += (size_t)C_*INNER_*2;
  bf16_t* Wot = (bf16_t*)(ws + off);                  off += (size_t)C_*INNER_*2;
  (void)ws_size; (void)in_sizes; (void)n_in; (void)out_size;

  k_detect<<<1, 64, 0, stream>>>((const unsigned char*)mask, flag);
  k_transpose<<<dim3(16,10), 256, 0, stream>>>(Wq, Wqt, C_, INNER_);
  k_transpose<<<dim3(16,10), 256, 0, stream>>>(Wk, Wkt, C_, INNER_);
  k_transpose<<<dim3(16,10), 256, 0, stream>>>(Wv, Wvt, C_, INNER_);
  k_transpose<<<dim3(10,16), 256, 0, stream>>>(Wo, Wot, INNER_, C_);
  k_maskcompact<<<4096, 256, 0, stream>>>(mask, flag, maskp);
  k_proj<0><<<dim3(128,4), 256, 0, stream>>>(x, nullptr, nullptr, Wqt, Qw);
  k_proj<1><<<dim3(132,4), 256, 0, stream>>>(nullptr, ctx, regt, Wkt, Kw);
  k_proj<2><<<dim3(132,4), 256, 0, stream>>>(nullptr, ctx, regt, Wvt, Vtw);
  k_attn<<<dim3(32,64), 256, 0, stream>>>(Qw, Kw, Vtw, maskp, Att);
  k_out<<<dim3(128,5), 256, 0, stream>>>(Att, Wot, bo, out);
}

// Round 2
// 312.572 us; speedup vs baseline: 1.3336x; 1.3336x over previous
//
#include <hip/hip_runtime.h>
#include <hip/hip_bf16.h>

#define B_ 8
#define L1_ 2048
#define L2_ 2048
#define C_ 320
#define H_ 8
#define D_ 64
#define NREG_ 4
#define INNER_ 512
#define LK_ 2052
#define LKP_ 2112   /* 33*64 padded key length */
#define NKV_TILES 33
#define LOG2E 1.44269504f

typedef __bf16 bf16_t;
typedef __attribute__((ext_vector_type(8))) __bf16 bf16x8;
typedef __attribute__((ext_vector_type(4))) __bf16 bf16x4;
typedef __attribute__((ext_vector_type(4))) float f32x4;

__device__ __forceinline__ f32x4 mfma16(bf16x8 a, bf16x8 b, f32x4 c){
  return __builtin_amdgcn_mfma_f32_16x16x32_bf16(a, b, c, 0, 0, 0);
}

__device__ __forceinline__ void gl_lds16(const char* g, char* l){
  __builtin_amdgcn_global_load_lds(
      (const __attribute__((address_space(1))) unsigned int*)g,
      (__attribute__((address_space(3))) unsigned int*)l, 16, 0, 0);
}

// K-tile rows are read with only row-bits {0,1,3,4} varying per fragment
// (bit 2 = T&1 is fixed) -> swizzle must use bits 0,1,3 to reach 8 columns.
__device__ __forceinline__ int swzK(int row){ return (row & 3) | ((row >> 1) & 4); }
// V-tile rows vary in bits 0..3 within a fragment read -> row&7 is fine.
__device__ __forceinline__ int swzV(int row){ return row & 7; }

// ---------------- mask dtype detection (parallel) ----------------
__global__ void k_detect(const unsigned char* mask, int* flag){
  int i = threadIdx.x;
  int bad = 0;
  for (int j = i; j < 256; j += 64)
    if ((j & 3) != 0 && mask[j] != 0) bad = 1;   // byte-sized bool layout
  unsigned long long bal = __ballot(bad);
  if (i == 0) *flag = (bal == 0ull) ? 1 : 0;     // 1 = int32, 0 = bool
}

// ---------------- weight transpose fp32[K][N] -> bf16[N][K] ----------------
__global__ void k_transpose(const float* __restrict__ W, bf16_t* __restrict__ Wt,
                            int K, int N){
  __shared__ float t[32][33];
  int n0 = blockIdx.x * 32, k0 = blockIdx.y * 32;
  int tx = threadIdx.x & 31, ty = threadIdx.x >> 5;
  for (int r = ty; r < 32; r += 8) t[r][tx] = W[(long)(k0 + r) * N + n0 + tx];
  __syncthreads();
  for (int r = ty; r < 32; r += 8) Wt[(long)(n0 + r) * K + k0 + tx] = (bf16_t)t[tx][r];
}

// ---------------- mask -> packed bits over padded kv domain [0,2112) ----------------
__global__ void k_maskcompact(const void* __restrict__ maskv, const int* __restrict__ flag,
                              unsigned int* __restrict__ maskp){
  int row = blockIdx.x * 4 + (threadIdx.x >> 6);   // 0..16383 = b*2048+q
  int lane = threadIdx.x & 63;
  const unsigned char* mb = (const unsigned char*)maskv;
  const int* mi = (const int*)maskv;
  int isInt = *flag;
  long base = (long)row * L2_;
  unsigned int* orow = maskp + (long)row * 66;
  for (int s = 0; s < 33; s++){
    int kv = s * 64 + lane;
    int vis = 0;
    if (kv < NREG_) vis = 1;
    else if (kv < LK_){
      long idx = base + (kv - NREG_);
      vis = isInt ? (mi[idx] != 0) : (mb[idx] != 0);
    }
    unsigned long long bal = __ballot(vis);
    if (lane == 0)      orow[2*s]   = (unsigned int)bal;
    else if (lane == 1) orow[2*s+1] = (unsigned int)(bal >> 32);
  }
}

// ---------------- projection GEMM: C[m][n] = A[m][0:320] @ W[0:320][n] ----------------
template<int MODE>
__global__ __launch_bounds__(256)
void k_proj(const float* __restrict__ A0, const float* __restrict__ ctx,
            const float* __restrict__ regtok, const bf16_t* __restrict__ Wt,
            bf16_t* __restrict__ out)
{
  __shared__ __align__(16) char As[128*64*2];
  __shared__ __align__(16) char Bs[128*64*2];
  int tid = threadIdx.x;
  int w = tid >> 6, lane = tid & 63, cl = lane & 15, cg = lane >> 4;
  int wr = w >> 1, wc = w & 1;
  int m0 = blockIdx.x * 128, n0 = blockIdx.y * 128;

  // hoist per-row source pointers (kills the per-kb integer divides)
  const float* srcs[8];
  #pragma unroll
  for (int c = 0; c < 8; c++){
    int e = c * 1024 + tid * 4;
    int row = e >> 6, k = e & 63;
    if (MODE == 0){
      srcs[c] = A0 + (long)(m0 + row) * C_ + k;
    } else {
      int rg = m0 + row;
      int b = rg / LKP_;
      int rr = rg - b * LKP_;
      const float* src = nullptr;
      if (rr < NREG_)    src = regtok + (long)rr * C_ + k;
      else if (rr < LK_) src = ctx + (long)(b * L1_ + rr - NREG_) * C_ + k;
      srcs[c] = src;
    }
  }

  f32x4 acc[4][4];
  #pragma unroll
  for (int i = 0; i < 4; i++)
    #pragma unroll
    for (int j = 0; j < 4; j++) acc[i][j] = (f32x4){0,0,0,0};

  for (int kb = 0; kb < 5; ++kb){
    int k0 = kb * 64;
    __syncthreads();
    #pragma unroll
    for (int c = 0; c < 8; c++){
      int e = c * 1024 + tid * 4;
      int row = e >> 6, k = e & 63;
      f32x4 v = (f32x4){0,0,0,0};
      if (MODE == 0) v = *(const f32x4*)(srcs[c] + k0);
      else if (srcs[c]) v = *(const f32x4*)(srcs[c] + k0);
      bf16x4 cv;
      cv[0]=(bf16_t)v[0]; cv[1]=(bf16_t)v[1]; cv[2]=(bf16_t)v[2]; cv[3]=(bf16_t)v[3];
      int off = (row << 7) + ((k << 1) ^ ((row & 7) << 4));
      *(bf16x4*)(As + off) = cv;
    }
    #pragma unroll
    for (int c = 0; c < 4; c++){
      int e = c * 2048 + tid * 8;
      int row = e >> 6, k = e & 63;
      bf16x8 v = *(const bf16x8*)(Wt + (long)(n0 + row) * C_ + k0 + k);
      int off = (row << 7) + ((k << 1) ^ ((row & 7) << 4));
      *(bf16x8*)(Bs + off) = v;
    }
    __syncthreads();
    #pragma unroll
    for (int kc = 0; kc < 2; kc++){
      int kk = kc * 32 + cg * 8;
      bf16x8 af[4], bfr[4];
      #pragma unroll
      for (int mt = 0; mt < 4; mt++){
        int row = wr * 64 + mt * 16 + cl;
        af[mt] = *(const bf16x8*)(As + (row << 7) + ((kk << 1) ^ ((row & 7) << 4)));
      }
      #pragma unroll
      for (int nt = 0; nt < 4; nt++){
        int row = wc * 64 + nt * 16 + cl;
        bfr[nt] = *(const bf16x8*)(Bs + (row << 7) + ((kk << 1) ^ ((row & 7) << 4)));
      }
      #pragma unroll
      for (int mt = 0; mt < 4; mt++)
        #pragma unroll
        for (int nt = 0; nt < 4; nt++)
          acc[mt][nt] = mfma16(af[mt], bfr[nt], acc[mt][nt]);
    }
  }

  #pragma unroll
  for (int mt = 0; mt < 4; mt++){
    #pragma unroll
    for (int nt = 0; nt < 4; nt++){
      f32x4 v = acc[mt][nt];
      int row = m0 + wr * 64 + mt * 16 + cg * 4;
      int col = n0 + wc * 64 + nt * 16 + cl;
      int h = col >> 6, d = col & 63;
      if (MODE == 0){
        int b = row >> 11, l1 = row & 2047;
        bf16_t* p = out + ((long)((b * H_ + h) * L1_ + l1)) * D_ + d;
        #pragma unroll
        for (int r = 0; r < 4; r++) p[r * D_] = (bf16_t)v[r];
      } else if (MODE == 1){
        int b = row / LKP_, rr = row - b * LKP_;
        bf16_t* p = out + ((long)((b * H_ + h) * LKP_ + rr)) * D_ + d;
        #pragma unroll
        for (int r = 0; r < 4; r++) p[r * D_] = (bf16_t)v[r];
      } else {
        int b = row / LKP_, rr = row - b * LKP_;
        bf16x4 cv;
        cv[0]=(bf16_t)v[0]; cv[1]=(bf16_t)v[1]; cv[2]=(bf16_t)v[2]; cv[3]=(bf16_t)v[3];
        *(bf16x4*)(out + ((long)((b * H_ + h) * D_ + d)) * LKP_ + rr) = cv;
      }
    }
  }
}

// ---------------- flash attention, swapped-QK^T / lane-local softmax ----------------
// block = 4 waves; wave handles 32 q-rows (2 groups of 16); 128 q-rows per block.
// S^T = mfma(K,Q): lane holds q=cl, kv = 32(T>>1)+8cg+4(T&1)+r -> P is already the
// PV A-fragment layout (k=8cg+j). No P LDS round-trip, no per-tile shuffles.
__global__ __launch_bounds__(256)
void k_attn(const bf16_t* __restrict__ Q, const bf16_t* __restrict__ K,
            const bf16_t* __restrict__ Vt, const unsigned int* __restrict__ maskp,
            bf16_t* __restrict__ att)
{
  __shared__ __align__(16) char smem[32768]; // 2 bufs x (8K K + 8K Vt)
  const int bh = blockIdx.y, b = bh >> 3, h = bh & 7;
  const int tid = threadIdx.x, w = tid >> 6, lane = tid & 63;
  const int cl = lane & 15, cg = lane >> 4;
  const int qw = blockIdx.x * 128 + w * 32;
  const float CS = 0.125f * LOG2E;   // scale folded into log2 domain

  const char* Kg = (const char*)(K + (long)bh * LKP_ * D_);
  const char* Vg = (const char*)(Vt + (long)bh * D_ * LKP_);

  bf16x8 qf[2][2];
  const unsigned int* mrow[2];
  #pragma unroll
  for (int qg = 0; qg < 2; qg++){
    const bf16_t* Qb = Q + ((long)bh * L1_ + qw + qg*16 + cl) * D_;
    qf[qg][0] = *(const bf16x8*)(Qb + cg*8);
    qf[qg][1] = *(const bf16x8*)(Qb + 32 + cg*8);
    mrow[qg] = maskp + (long)(b * L1_ + qw + qg*16 + cl) * 66;
  }

  f32x4 o[2][4];
  f32x4 ssum[2];
  float M[2] = {-1e30f, -1e30f};
  #pragma unroll
  for (int qg = 0; qg < 2; qg++){
    ssum[qg] = (f32x4){0,0,0,0};
    #pragma unroll
    for (int dt = 0; dt < 4; dt++) o[qg][dt] = (f32x4){0,0,0,0};
  }

  auto stage = [&](int buf, int t){
    char* base = smem + buf * 16384;
    #pragma unroll
    for (int c = 0; c < 2; c++){
      int p = c * 4096 + tid * 16;
      int row = p >> 7, ir = p & 127;
      gl_lds16(Kg + (long)(t * 64 + row) * 128 + (ir ^ (swzK(row) << 4)), base + p);
    }
    #pragma unroll
    for (int c = 0; c < 2; c++){
      int p = c * 4096 + tid * 16;
      int row = p >> 7, ir = p & 127;
      gl_lds16(Vg + (long)row * (LKP_ * 2) + t * 128 + (ir ^ (swzV(row) << 4)), base + 8192 + p);
    }
  };

  stage(0, 0);
  asm volatile("s_waitcnt vmcnt(0)" ::: "memory");
  __syncthreads();

  for (int t = 0; t < NKV_TILES; ++t){
    int cur = t & 1;
    uint2 wd[2];
    #pragma unroll
    for (int qg = 0; qg < 2; qg++) wd[qg] = *(const uint2*)(mrow[qg] + 2*t);
    if (t + 1 < NKV_TILES) stage(cur ^ 1, t + 1);
    const char* Kb = smem + cur * 16384;
    const char* Vb = Kb + 8192;

    // S^T: rows kv (interleaved map), cols q
    f32x4 s[2][4];
    #pragma unroll
    for (int T = 0; T < 4; T++){
      int row = 32*(T>>1) + 8*(cl>>2) + 4*(T&1) + (cl&3);
      int sw = swzK(row) << 4;
      const char* rp = Kb + (row << 7);
      bf16x8 kf0 = *(const bf16x8*)(rp + ((16*cg) ^ sw));
      bf16x8 kf1 = *(const bf16x8*)(rp + ((64 + 16*cg) ^ sw));
      #pragma unroll
      for (int qg = 0; qg < 2; qg++){
        f32x4 z = (f32x4){0,0,0,0};
        z = mfma16(kf0, qf[qg][0], z);
        z = mfma16(kf1, qf[qg][1], z);
        s[qg][T] = z;
      }
    }

    // defer-max: per-lane max + wave-uniform trigger (mask never affects max)
    float hm[2];
    int need = 0;
    #pragma unroll
    for (int qg = 0; qg < 2; qg++){
      float a0 = fmaxf(fmaxf(s[qg][0][0], s[qg][0][1]), fmaxf(s[qg][0][2], s[qg][0][3]));
      float a1 = fmaxf(fmaxf(s[qg][1][0], s[qg][1][1]), fmaxf(s[qg][1][2], s[qg][1][3]));
      float a2 = fmaxf(fmaxf(s[qg][2][0], s[qg][2][1]), fmaxf(s[qg][2][2], s[qg][2][3]));
      float a3 = fmaxf(fmaxf(s[qg][3][0], s[qg][3][1]), fmaxf(s[qg][3][2], s[qg][3][3]));
      hm[qg] = fmaxf(fmaxf(a0, a1), fmaxf(a2, a3)) * CS;
      need |= (hm[qg] > M[qg] + 8.f) ? 1 : 0;
    }
    if (__any(need)){
      #pragma unroll
      for (int qg = 0; qg < 2; qg++){
        float v = fmaxf(hm[qg], __shfl_xor(hm[qg], 16));
        v = fmaxf(v, __shfl_xor(v, 32));
        float mnew = fmaxf(M[qg], v);
        float f = exp2f(M[qg] - mnew);
        M[qg] = mnew;
        ssum[qg] *= f;
        float fr0 = __shfl(f, (lane & 48) | (cg*4 + 0));
        float fr1 = __shfl(f, (lane & 48) | (cg*4 + 1));
        float fr2 = __shfl(f, (lane & 48) | (cg*4 + 2));
        float fr3 = __shfl(f, (lane & 48) | (cg*4 + 3));
        f32x4 fv = (f32x4){fr0, fr1, fr2, fr3};
        #pragma unroll
        for (int dt = 0; dt < 4; dt++) o[qg][dt] *= fv;
      }
    }

    // p = exp2(z*CS - M), mask zeroes p, pack directly into PV A-fragments
    bf16x8 pa[2][2];
    #pragma unroll
    for (int qg = 0; qg < 2; qg++){
      float nM = -M[qg];
      #pragma unroll
      for (int T = 0; T < 4; T++){
        unsigned wsel = (T < 2) ? wd[qg].x : wd[qg].y;
        unsigned nib = (wsel >> (8*cg + 4*(T&1))) & 0xFu;
        float p0 = exp2f(fmaf(s[qg][T][0], CS, nM));
        float p1 = exp2f(fmaf(s[qg][T][1], CS, nM));
        float p2 = exp2f(fmaf(s[qg][T][2], CS, nM));
        float p3 = exp2f(fmaf(s[qg][T][3], CS, nM));
        p0 = (nib & 1u) ? p0 : 0.f;
        p1 = (nib & 2u) ? p1 : 0.f;
        p2 = (nib & 4u) ? p2 : 0.f;
        p3 = (nib & 8u) ? p3 : 0.f;
        ssum[qg] += (f32x4){p0, p1, p2, p3};
        int a = T >> 1, jb = (T & 1) * 4;
        pa[qg][a][jb+0] = (bf16_t)p0;
        pa[qg][a][jb+1] = (bf16_t)p1;
        pa[qg][a][jb+2] = (bf16_t)p2;
        pa[qg][a][jb+3] = (bf16_t)p3;
      }
    }

    // O += P @ V ; V-fragments shared across both q-groups
    #pragma unroll
    for (int dt = 0; dt < 4; dt++){
      int row = 16*dt + cl;
      int sw = swzV(row) << 4;
      const char* rp = Vb + (row << 7);
      bf16x8 vf0 = *(const bf16x8*)(rp + ((16*cg) ^ sw));
      bf16x8 vf1 = *(const bf16x8*)(rp + ((64 + 16*cg) ^ sw));
      #pragma unroll
      for (int qg = 0; qg < 2; qg++){
        o[qg][dt] = mfma16(pa[qg][0], vf0, o[qg][dt]);
        o[qg][dt] = mfma16(pa[qg][1], vf1, o[qg][dt]);
      }
    }

    asm volatile("s_waitcnt vmcnt(0)" ::: "memory");
    __syncthreads();
  }

  // epilogue: combine partial sums (2 shuffles), normalize, store
  #pragma unroll
  for (int qg = 0; qg < 2; qg++){
    float sl = ssum[qg][0] + ssum[qg][1] + ssum[qg][2] + ssum[qg][3];
    sl += __shfl_xor(sl, 16);
    sl += __shfl_xor(sl, 32);
    float inv = 1.0f / sl;
    float ir0 = __shfl(inv, (lane & 48) | (cg*4 + 0));
    float ir1 = __shfl(inv, (lane & 48) | (cg*4 + 1));
    float ir2 = __shfl(inv, (lane & 48) | (cg*4 + 2));
    float ir3 = __shfl(inv, (lane & 48) | (cg*4 + 3));
    int qbase = qw + qg*16 + cg*4;
    #pragma unroll
    for (int dt = 0; dt < 4; dt++){
      bf16_t* op = att + ((long)(b * L1_) + qbase) * INNER_ + h * D_ + 16*dt + cl;
      op[0] = (bf16_t)(o[qg][dt][0] * ir0);
      op[INNER_] = (bf16_t)(o[qg][dt][1] * ir1);
      op[2*INNER_] = (bf16_t)(o[qg][dt][2] * ir2);
      op[3*INNER_] = (bf16_t)(o[qg][dt][3] * ir3);
    }
  }
}

// ---------------- output GEMM: out[m][c] = att[m][:512] @ Wo + bo ----------------
__global__ __launch_bounds__(256)
void k_out(const bf16_t* __restrict__ A, const bf16_t* __restrict__ Wot,
           const float* __restrict__ bo, float* __restrict__ out)
{
  __shared__ __align__(16) char As[128*64*2];
  __shared__ __align__(16) char Bs[64*64*2];
  int tid = threadIdx.x;
  int w = tid >> 6, lane = tid & 63, cl = lane & 15, cg = lane >> 4;
  int wr = w >> 1, wc = w & 1;
  int m0 = blockIdx.x * 128, n0 = blockIdx.y * 64;

  f32x4 acc[4][2];
  #pragma unroll
  for (int i = 0; i < 4; i++)
    #pragma unroll
    for (int j = 0; j < 2; j++) acc[i][j] = (f32x4){0,0,0,0};

  for (int kb = 0; kb < 8; kb++){
    int k0 = kb * 64;
    __syncthreads();
    #pragma unroll
    for (int c = 0; c < 4; c++){
      int e = c * 2048 + tid * 8;
      int row = e >> 6, k = e & 63;
      bf16x8 v = *(const bf16x8*)(A + (long)(m0 + row) * INNER_ + k0 + k);
      *(bf16x8*)(As + (row << 7) + ((k << 1) ^ ((row & 7) << 4))) = v;
    }
    #pragma unroll
    for (int c = 0; c < 2; c++){
      int e = c * 2048 + tid * 8;
      int row = e >> 6, k = e & 63;
      bf16x8 v = *(const bf16x8*)(Wot + (long)(n0 + row) * INNER_ + k0 + k);
      *(bf16x8*)(Bs + (row << 7) + ((k << 1) ^ ((row & 7) << 4))) = v;
    }
    __syncthreads();
    #pragma unroll
    for (int kc = 0; kc < 2; kc++){
      int kk = kc * 32 + cg * 8;
      bf16x8 af[4], bfr[2];
      #pragma unroll
      for (int mt = 0; mt < 4; mt++){
        int row = wr * 64 + mt * 16 + cl;
        af[mt] = *(const bf16x8*)(As + (row << 7) + ((kk << 1) ^ ((row & 7) << 4)));
      }
      #pragma unroll
      for (int nt = 0; nt < 2; nt++){
        int row = wc * 32 + nt * 16 + cl;
        bfr[nt] = *(const bf16x8*)(Bs + (row << 7) + ((kk << 1) ^ ((row & 7) << 4)));
      }
      #pragma unroll
      for (int mt = 0; mt < 4; mt++)
        #pragma unroll
        for (int nt = 0; nt < 2; nt++)
          acc[mt][nt] = mfma16(af[mt], bfr[nt], acc[mt][nt]);
    }
  }
  #pragma unroll
  for (int mt = 0; mt < 4; mt++)
    #pragma unroll
    for (int nt = 0; nt < 2; nt++){
      int row = m0 + wr * 64 + mt * 16 + cg * 4;
      int col = n0 + wc * 32 + nt * 16 + cl;
      float bias = bo[col];
      #pragma unroll
      for (int r = 0; r < 4; r++)
        out[(long)(row + r) * C_ + col] = acc[mt][nt][r] + bias;
    }
}

extern "C" void kernel_launch(void* const* d_in, const int* in_sizes, int n_in,
                              void* d_out, int out_size, void* d_ws, size_t ws_size,
                              hipStream_t stream)
{
  const float* x    = (const float*)d_in[0];
  const float* ctx  = (const float*)d_in[1];
  const void*  mask = d_in[2];
  const float* Wq   = (const float*)d_in[3];
  const float* Wk   = (const float*)d_in[4];
  const float* Wv   = (const float*)d_in[5];
  const float* Wo   = (const float*)d_in[6];
  const float* bo   = (const float*)d_in[7];
  const float* regt = (const float*)d_in[8];
  float* out = (float*)d_out;

  char* ws = (char*)d_ws;
  size_t off = 0;
  int* flag = (int*)ws;                               off = 256;
  unsigned int* maskp = (unsigned int*)(ws + off);    off += (size_t)16384 * 66 * 4;
  bf16_t* Qw  = (bf16_t*)(ws + off);                  off += (size_t)B_*H_*L1_*D_*2;
  bf16_t* Kw  = (bf16_t*)(ws + off);                  off += (size_t)B_*H_*LKP_*D_*2;
  bf16_t* Vtw = (bf16_t*)(ws + off);                  off += (size_t)B_*H_*D_*LKP_*2;
  bf16_t* Att = (bf16_t*)(ws + off);                  off += (size_t)B_*L1_*INNER_*2;
  bf16_t* Wqt = (bf16_t*)(ws + off);                  off += (size_t)C_*INNER_*2;
  bf16_t* Wkt = (bf16_t*)(ws + off);                  off += (size_t)C_*INNER_*2;
  bf16_t* Wvt = (bf16_t*)(ws + off);                  off += (size_t)C_*INNER_*2;
  bf16_t* Wot = (bf16_t*)(ws + off);                  off += (size_t)C_*INNER_*2;
  (void)ws_size; (void)in_sizes; (void)n_in; (void)out_size;

  k_detect<<<1, 64, 0, stream>>>((const unsigned char*)mask, flag);
  k_transpose<<<dim3(16,10), 256, 0, stream>>>(Wq, Wqt, C_, INNER_);
  k_transpose<<<dim3(16,10), 256, 0, stream>>>(Wk, Wkt, C_, INNER_);
  k_transpose<<<dim3(16,10), 256, 0, stream>>>(Wv, Wvt, C_, INNER_);
  k_transpose<<<dim3(10,16), 256, 0, stream>>>(Wo, Wot, INNER_, C_);
  k_maskcompact<<<4096, 256, 0, stream>>>(mask, flag, maskp);
  k_proj<0><<<dim3(128,4), 256, 0, stream>>>(x, nullptr, nullptr, Wqt, Qw);
  k_proj<1><<<dim3(132,4), 256, 0, stream>>>(nullptr, ctx, regt, Wkt, Kw);
  k_proj<2><<<dim3(132,4), 256, 0, stream>>>(nullptr, ctx, regt, Wvt, Vtw);
  k_attn<<<dim3(16,64), 256, 0, stream>>>(Qw, Kw, Vtw, maskp, Att);
  k_out<<<dim3(128,5), 256, 0, stream>>>(Att, Wot, bo, out);
}

// Round 3
// 295.081 us; speedup vs baseline: 1.4127x; 1.0593x over previous
//
#include <hip/hip_runtime.h>
#include <hip/hip_bf16.h>

#define B_ 8
#define L1_ 2048
#define L2_ 2048
#define C_ 320
#define H_ 8
#define D_ 64
#define NREG_ 4
#define INNER_ 512
#define LK_ 2052
#define LKP_ 2112   /* 33*64 padded key length */
#define NKV_TILES 33
#define LOG2E 1.44269504f
#define QSCALE (0.125f * LOG2E)   /* folded into Q at projection time */

typedef __bf16 bf16_t;
typedef __attribute__((ext_vector_type(8))) __bf16 bf16x8;
typedef __attribute__((ext_vector_type(4))) __bf16 bf16x4;
typedef __attribute__((ext_vector_type(4))) float f32x4;

__device__ __forceinline__ f32x4 mfma16(bf16x8 a, bf16x8 b, f32x4 c){
  return __builtin_amdgcn_mfma_f32_16x16x32_bf16(a, b, c, 0, 0, 0);
}

__device__ __forceinline__ void gl_lds16(const char* g, char* l){
  __builtin_amdgcn_global_load_lds(
      (const __attribute__((address_space(1))) unsigned int*)g,
      (__attribute__((address_space(3))) unsigned int*)l, 16, 0, 0);
}

// K-tile rows are read with only row-bits {0,1,3,4} varying per fragment
// (bit 2 = T&1 is fixed) -> swizzle must use bits 0,1,3 to reach 8 columns.
__device__ __forceinline__ int swzK(int row){ return (row & 3) | ((row >> 1) & 4); }
__device__ __forceinline__ int swzV(int row){ return row & 7; }

// ---------------- mask dtype detection (parallel) ----------------
__global__ void k_detect(const unsigned char* mask, int* flag){
  int i = threadIdx.x;
  int bad = 0;
  for (int j = i; j < 256; j += 64)
    if ((j & 3) != 0 && mask[j] != 0) bad = 1;   // byte-sized bool layout
  unsigned long long bal = __ballot(bad);
  if (i == 0) *flag = (bal == 0ull) ? 1 : 0;     // 1 = int32, 0 = bool
}

// ---------------- all 4 weight transposes in one launch ----------------
// z<3: W (320x512) -> Wt[512][320] ; z==3: Wo (512x320) -> Wot[320][512]
__global__ void k_transpose(const float* __restrict__ Wq, const float* __restrict__ Wk,
                            const float* __restrict__ Wv, const float* __restrict__ Wo,
                            bf16_t* __restrict__ Wqt, bf16_t* __restrict__ Wkt,
                            bf16_t* __restrict__ Wvt, bf16_t* __restrict__ Wot){
  int z = blockIdx.z;
  int K = (z < 3) ? C_ : INNER_;
  int N = (z < 3) ? INNER_ : C_;
  if (blockIdx.x * 32 >= N || blockIdx.y * 32 >= K) return;
  const float* W = (z == 0) ? Wq : (z == 1) ? Wk : (z == 2) ? Wv : Wo;
  bf16_t* Wt = (z == 0) ? Wqt : (z == 1) ? Wkt : (z == 2) ? Wvt : Wot;
  __shared__ float t[32][33];
  int n0 = blockIdx.x * 32, k0 = blockIdx.y * 32;
  int tx = threadIdx.x & 31, ty = threadIdx.x >> 5;
  for (int r = ty; r < 32; r += 8) t[r][tx] = W[(long)(k0 + r) * N + n0 + tx];
  __syncthreads();
  for (int r = ty; r < 32; r += 8) Wt[(long)(n0 + r) * K + k0 + tx] = (bf16_t)t[tx][r];
}

// ---------------- mask -> packed bits over padded kv domain [0,2112) ----------------
__global__ void k_maskcompact(const void* __restrict__ maskv, const int* __restrict__ flag,
                              unsigned int* __restrict__ maskp){
  int row = blockIdx.x * 4 + (threadIdx.x >> 6);   // 0..16383 = b*2048+q
  int lane = threadIdx.x & 63;
  const unsigned char* mb = (const unsigned char*)maskv;
  const int* mi = (const int*)maskv;
  int isInt = *flag;
  long base = (long)row * L2_;
  unsigned int* orow = maskp + (long)row * 66;
  for (int s = 0; s < 33; s++){
    int kv = s * 64 + lane;
    int vis = 0;
    if (kv < NREG_) vis = 1;
    else if (kv < LK_){
      long idx = base + (kv - NREG_);
      vis = isInt ? (mi[idx] != 0) : (mb[idx] != 0);
    }
    unsigned long long bal = __ballot(vis);
    if (lane == 0)      orow[2*s]   = (unsigned int)bal;
    else if (lane == 1) orow[2*s+1] = (unsigned int)(bal >> 32);
  }
}

// ---------------- fused Q/K/V projection GEMMs (mode = blockIdx.z) ----------------
// mode 0: A = x (M=16384), out Q (pre-scaled by QSCALE)
// mode 1: A = [reg|context|0], out K[bh][rr][d]
// mode 2: same A, out Vt[bh][d][rr] (transposed)
__global__ __launch_bounds__(256)
void k_proj(const float* __restrict__ x, const float* __restrict__ ctx,
            const float* __restrict__ regtok,
            const bf16_t* __restrict__ Wqt, const bf16_t* __restrict__ Wkt,
            const bf16_t* __restrict__ Wvt,
            bf16_t* __restrict__ Qw, bf16_t* __restrict__ Kw, bf16_t* __restrict__ Vtw)
{
  int mode = blockIdx.z;
  if (mode == 0 && blockIdx.x >= 128) return;
  const bf16_t* Wt = (mode == 0) ? Wqt : (mode == 1) ? Wkt : Wvt;
  bf16_t* out = (mode == 0) ? Qw : (mode == 1) ? Kw : Vtw;

  __shared__ __align__(16) char As[128*64*2];
  __shared__ __align__(16) char Bs[128*64*2];
  int tid = threadIdx.x;
  int w = tid >> 6, lane = tid & 63, cl = lane & 15, cg = lane >> 4;
  int wr = w >> 1, wc = w & 1;
  int m0 = blockIdx.x * 128, n0 = blockIdx.y * 128;

  const float* srcs[8];
  #pragma unroll
  for (int c = 0; c < 8; c++){
    int e = c * 1024 + tid * 4;
    int row = e >> 6, k = e & 63;
    if (mode == 0){
      srcs[c] = x + (long)(m0 + row) * C_ + k;
    } else {
      int rg = m0 + row;
      int b = rg / LKP_;
      int rr = rg - b * LKP_;
      const float* src = nullptr;
      if (rr < NREG_)    src = regtok + (long)rr * C_ + k;
      else if (rr < LK_) src = ctx + (long)(b * L1_ + rr - NREG_) * C_ + k;
      srcs[c] = src;
    }
  }

  f32x4 acc[4][4];
  #pragma unroll
  for (int i = 0; i < 4; i++)
    #pragma unroll
    for (int j = 0; j < 4; j++) acc[i][j] = (f32x4){0,0,0,0};

  for (int kb = 0; kb < 5; ++kb){
    int k0 = kb * 64;
    __syncthreads();
    #pragma unroll
    for (int c = 0; c < 8; c++){
      int e = c * 1024 + tid * 4;
      int row = e >> 6, k = e & 63;
      f32x4 v = (f32x4){0,0,0,0};
      if (srcs[c]) v = *(const f32x4*)(srcs[c] + k0);
      bf16x4 cv;
      cv[0]=(bf16_t)v[0]; cv[1]=(bf16_t)v[1]; cv[2]=(bf16_t)v[2]; cv[3]=(bf16_t)v[3];
      int off = (row << 7) + ((k << 1) ^ ((row & 7) << 4));
      *(bf16x4*)(As + off) = cv;
    }
    #pragma unroll
    for (int c = 0; c < 4; c++){
      int e = c * 2048 + tid * 8;
      int row = e >> 6, k = e & 63;
      bf16x8 v = *(const bf16x8*)(Wt + (long)(n0 + row) * C_ + k0 + k);
      int off = (row << 7) + ((k << 1) ^ ((row & 7) << 4));
      *(bf16x8*)(Bs + off) = v;
    }
    __syncthreads();
    #pragma unroll
    for (int kc = 0; kc < 2; kc++){
      int kk = kc * 32 + cg * 8;
      bf16x8 af[4], bfr[4];
      #pragma unroll
      for (int mt = 0; mt < 4; mt++){
        int row = wr * 64 + mt * 16 + cl;
        af[mt] = *(const bf16x8*)(As + (row << 7) + ((kk << 1) ^ ((row & 7) << 4)));
      }
      #pragma unroll
      for (int nt = 0; nt < 4; nt++){
        int row = wc * 64 + nt * 16 + cl;
        bfr[nt] = *(const bf16x8*)(Bs + (row << 7) + ((kk << 1) ^ ((row & 7) << 4)));
      }
      #pragma unroll
      for (int mt = 0; mt < 4; mt++)
        #pragma unroll
        for (int nt = 0; nt < 4; nt++)
          acc[mt][nt] = mfma16(af[mt], bfr[nt], acc[mt][nt]);
    }
  }

  #pragma unroll
  for (int mt = 0; mt < 4; mt++){
    #pragma unroll
    for (int nt = 0; nt < 4; nt++){
      f32x4 v = acc[mt][nt];
      int row = m0 + wr * 64 + mt * 16 + cg * 4;
      int col = n0 + wc * 64 + nt * 16 + cl;
      int h = col >> 6, d = col & 63;
      if (mode == 0){
        int b = row >> 11, l1 = row & 2047;
        bf16_t* p = out + ((long)((b * H_ + h) * L1_ + l1)) * D_ + d;
        #pragma unroll
        for (int r = 0; r < 4; r++) p[r * D_] = (bf16_t)(v[r] * QSCALE);
      } else if (mode == 1){
        int b = row / LKP_, rr = row - b * LKP_;
        bf16_t* p = out + ((long)((b * H_ + h) * LKP_ + rr)) * D_ + d;
        #pragma unroll
        for (int r = 0; r < 4; r++) p[r * D_] = (bf16_t)v[r];
      } else {
        int b = row / LKP_, rr = row - b * LKP_;
        bf16x4 cv;
        cv[0]=(bf16_t)v[0]; cv[1]=(bf16_t)v[1]; cv[2]=(bf16_t)v[2]; cv[3]=(bf16_t)v[3];
        *(bf16x4*)(out + ((long)((b * H_ + h) * D_ + d)) * LKP_ + rr) = cv;
      }
    }
  }
}

// ---------------- flash attention ----------------
// swapped-QK^T / lane-local softmax; ssum via MFMA(ones); depth-2 K pipeline
// (3-buf K, 2-buf V, counted vmcnt(2), raw barrier); XCD-aware block remap.
__global__ __launch_bounds__(256)
void k_attn(const bf16_t* __restrict__ Q, const bf16_t* __restrict__ K,
            const bf16_t* __restrict__ Vt, const unsigned int* __restrict__ maskp,
            bf16_t* __restrict__ att)
{
  __shared__ __align__(16) char smem[40960]; // K: 3 x 8KB @ 0, V: 2 x 8KB @ 24576
  // XCD-aware remap: each bh's 16 q-blocks on one XCD (8 bh per XCD)
  int lin = blockIdx.x + 16 * blockIdx.y;     // 0..1023
  int xcd = lin & 7, idx = lin >> 3;          // 128 blocks per xcd
  int bh = xcd * 8 + (idx >> 4);
  int qb = idx & 15;
  const int b = bh >> 3, h = bh & 7;
  const int tid = threadIdx.x, w = tid >> 6, lane = tid & 63;
  const int cl = lane & 15, cg = lane >> 4;
  const int qw = qb * 128 + w * 32;

  const char* Kg = (const char*)(K + (long)bh * LKP_ * D_);
  const char* Vg = (const char*)(Vt + (long)bh * D_ * LKP_);

  bf16x8 qf[2][2];
  const unsigned int* mrow[2];
  #pragma unroll
  for (int qg = 0; qg < 2; qg++){
    const bf16_t* Qb = Q + ((long)bh * L1_ + qw + qg*16 + cl) * D_;
    qf[qg][0] = *(const bf16x8*)(Qb + cg*8);
    qf[qg][1] = *(const bf16x8*)(Qb + 32 + cg*8);
    mrow[qg] = maskp + (long)(b * L1_ + qw + qg*16 + cl) * 66;
  }

  bf16x8 ones8;
  #pragma unroll
  for (int i = 0; i < 8; i++) ones8[i] = (bf16_t)1.0f;

  f32x4 o[2][4];
  f32x4 sacc[2];
  float M[2] = {-1e30f, -1e30f};
  #pragma unroll
  for (int qg = 0; qg < 2; qg++){
    sacc[qg] = (f32x4){0,0,0,0};
    #pragma unroll
    for (int dt = 0; dt < 4; dt++) o[qg][dt] = (f32x4){0,0,0,0};
  }

  auto stageK = [&](int slot, int t){
    char* base = smem + slot * 8192;
    #pragma unroll
    for (int c = 0; c < 2; c++){
      int p = c * 4096 + tid * 16;
      int row = p >> 7, ir = p & 127;
      gl_lds16(Kg + (long)(t * 64 + row) * 128 + (ir ^ (swzK(row) << 4)), base + p);
    }
  };
  auto stageV = [&](int slot, int t){
    char* base = smem + 24576 + slot * 8192;
    #pragma unroll
    for (int c = 0; c < 2; c++){
      int p = c * 4096 + tid * 16;
      int row = p >> 7, ir = p & 127;
      gl_lds16(Vg + (long)row * (LKP_ * 2) + t * 128 + (ir ^ (swzV(row) << 4)), base + 8192 + p - 8192);
    }
  };

  // prologue: K(0), K(1), V(0), wd(0); full drain
  stageK(0, 0);
  stageK(1, 1);
  stageV(0, 0);
  uint2 wd_cur[2];
  #pragma unroll
  for (int qg = 0; qg < 2; qg++) wd_cur[qg] = *(const uint2*)(mrow[qg]);
  asm volatile("s_waitcnt vmcnt(0)" ::: "memory");
  __syncthreads();

  for (int t = 0; t < NKV_TILES; ++t){
    // per-iter vmem budget: 2 wd + 2 V-gl_lds + 2 K-gl_lds = 6; end keeps K(t+2):2
    int tn = (t + 1 < NKV_TILES) ? t + 1 : NKV_TILES - 1;
    int tk = (t + 2 < NKV_TILES) ? t + 2 : NKV_TILES - 1;
    uint2 wd_nxt[2];
    #pragma unroll
    for (int qg = 0; qg < 2; qg++) wd_nxt[qg] = *(const uint2*)(mrow[qg] + 2*tn);
    stageV((t + 1) & 1, tn);
    stageK((t + 2) % 3, tk);

    const char* Kb = smem + (t % 3) * 8192;
    const char* Vb = smem + 24576 + (t & 1) * 8192;

    // S^T: rows kv (interleaved map), cols q
    f32x4 s[2][4];
    #pragma unroll
    for (int T = 0; T < 4; T++){
      int row = 32*(T>>1) + 8*(cl>>2) + 4*(T&1) + (cl&3);
      int sw = swzK(row) << 4;
      const char* rp = Kb + (row << 7);
      bf16x8 kf0 = *(const bf16x8*)(rp + ((16*cg) ^ sw));
      bf16x8 kf1 = *(const bf16x8*)(rp + ((64 + 16*cg) ^ sw));
      #pragma unroll
      for (int qg = 0; qg < 2; qg++){
        f32x4 z = (f32x4){0,0,0,0};
        z = mfma16(kf0, qf[qg][0], z);
        z = mfma16(kf1, qf[qg][1], z);
        s[qg][T] = z;
      }
    }

    // defer-max (scores already in log2 domain via QSCALE): max3 tree
    float hm[2];
    int need = 0;
    #pragma unroll
    for (int qg = 0; qg < 2; qg++){
      float v0=s[qg][0][0], v1=s[qg][0][1], v2=s[qg][0][2], v3=s[qg][0][3];
      float v4=s[qg][1][0], v5=s[qg][1][1], v6=s[qg][1][2], v7=s[qg][1][3];
      float v8=s[qg][2][0], v9=s[qg][2][1], v10=s[qg][2][2], v11=s[qg][2][3];
      float v12=s[qg][3][0], v13=s[qg][3][1], v14=s[qg][3][2], v15=s[qg][3][3];
      float a = fmaxf(fmaxf(v0,v1),v2);
      float bb = fmaxf(fmaxf(v3,v4),v5);
      float c = fmaxf(fmaxf(v6,v7),v8);
      float d = fmaxf(fmaxf(v9,v10),v11);
      float e = fmaxf(fmaxf(v12,v13),v14);
      float f2 = fmaxf(fmaxf(a,bb),c);
      float g = fmaxf(fmaxf(d,e),v15);
      hm[qg] = fmaxf(f2, g);
      need |= (hm[qg] > M[qg] + 8.f) ? 1 : 0;
    }
    if (__any(need)){
      #pragma unroll
      for (int qg = 0; qg < 2; qg++){
        float v = fmaxf(hm[qg], __shfl_xor(hm[qg], 16));
        v = fmaxf(v, __shfl_xor(v, 32));
        float mnew = fmaxf(M[qg], v);
        float f = exp2f(M[qg] - mnew);
        M[qg] = mnew;
        sacc[qg] *= f;
        float fr0 = __shfl(f, (lane & 48) | (cg*4 + 0));
        float fr1 = __shfl(f, (lane & 48) | (cg*4 + 1));
        float fr2 = __shfl(f, (lane & 48) | (cg*4 + 2));
        float fr3 = __shfl(f, (lane & 48) | (cg*4 + 3));
        f32x4 fv = (f32x4){fr0, fr1, fr2, fr3};
        #pragma unroll
        for (int dt = 0; dt < 4; dt++) o[qg][dt] *= fv;
      }
    }

    // p = exp2(z - M), mask zeroes p, pack directly into PV A-fragments
    bf16x8 pa[2][2];
    #pragma unroll
    for (int qg = 0; qg < 2; qg++){
      float nM = -M[qg];
      #pragma unroll
      for (int T = 0; T < 4; T++){
        unsigned wsel = (T < 2) ? wd_cur[qg].x : wd_cur[qg].y;
        unsigned nib = (wsel >> (8*cg + 4*(T&1))) & 0xFu;
        float p0 = exp2f(s[qg][T][0] + nM);
        float p1 = exp2f(s[qg][T][1] + nM);
        float p2 = exp2f(s[qg][T][2] + nM);
        float p3 = exp2f(s[qg][T][3] + nM);
        p0 = (nib & 1u) ? p0 : 0.f;
        p1 = (nib & 2u) ? p1 : 0.f;
        p2 = (nib & 4u) ? p2 : 0.f;
        p3 = (nib & 8u) ? p3 : 0.f;
        int a = T >> 1, jb = (T & 1) * 4;
        pa[qg][a][jb+0] = (bf16_t)p0;
        pa[qg][a][jb+1] = (bf16_t)p1;
        pa[qg][a][jb+2] = (bf16_t)p2;
        pa[qg][a][jb+3] = (bf16_t)p3;
      }
      // row-sums on the MFMA pipe: sacc[r] = sum_k P[q=cl][k] for all r
      sacc[qg] = mfma16(ones8, pa[qg][0], sacc[qg]);
      sacc[qg] = mfma16(ones8, pa[qg][1], sacc[qg]);
    }

    // O += P @ V ; V-fragments shared across both q-groups
    #pragma unroll
    for (int dt = 0; dt < 4; dt++){
      int row = 16*dt + cl;
      int sw = swzV(row) << 4;
      const char* rp = Vb + (row << 7);
      bf16x8 vf0 = *(const bf16x8*)(rp + ((16*cg) ^ sw));
      bf16x8 vf1 = *(const bf16x8*)(rp + ((64 + 16*cg) ^ sw));
      #pragma unroll
      for (int qg = 0; qg < 2; qg++){
        o[qg][dt] = mfma16(pa[qg][0], vf0, o[qg][dt]);
        o[qg][dt] = mfma16(pa[qg][1], vf1, o[qg][dt]);
      }
    }

    // keep K(t+2) in flight across the barrier; drain wd(t+1), V(t+1), K(t+1)
    asm volatile("s_waitcnt vmcnt(2)" ::: "memory");
    __builtin_amdgcn_s_barrier();
    wd_cur[0] = wd_nxt[0];
    wd_cur[1] = wd_nxt[1];
  }

  // epilogue: every lane holds its q=cl row-sum in sacc[qg][0]
  #pragma unroll
  for (int qg = 0; qg < 2; qg++){
    float inv = 1.0f / sacc[qg][0];
    float ir0 = __shfl(inv, (lane & 48) | (cg*4 + 0));
    float ir1 = __shfl(inv, (lane & 48) | (cg*4 + 1));
    float ir2 = __shfl(inv, (lane & 48) | (cg*4 + 2));
    float ir3 = __shfl(inv, (lane & 48) | (cg*4 + 3));
    int qbase = qw + qg*16 + cg*4;
    #pragma unroll
    for (int dt = 0; dt < 4; dt++){
      bf16_t* op = att + ((long)(b * L1_) + qbase) * INNER_ + h * D_ + 16*dt + cl;
      op[0] = (bf16_t)(o[qg][dt][0] * ir0);
      op[INNER_] = (bf16_t)(o[qg][dt][1] * ir1);
      op[2*INNER_] = (bf16_t)(o[qg][dt][2] * ir2);
      op[3*INNER_] = (bf16_t)(o[qg][dt][3] * ir3);
    }
  }
}

// ---------------- output GEMM: out[m][c] = att[m][:512] @ Wo + bo ----------------
__global__ __launch_bounds__(256)
void k_out(const bf16_t* __restrict__ A, const bf16_t* __restrict__ Wot,
           const float* __restrict__ bo, float* __restrict__ out)
{
  __shared__ __align__(16) char As[128*64*2];
  __shared__ __align__(16) char Bs[64*64*2];
  int tid = threadIdx.x;
  int w = tid >> 6, lane = tid & 63, cl = lane & 15, cg = lane >> 4;
  int wr = w >> 1, wc = w & 1;
  int m0 = blockIdx.x * 128, n0 = blockIdx.y * 64;

  f32x4 acc[4][2];
  #pragma unroll
  for (int i = 0; i < 4; i++)
    #pragma unroll
    for (int j = 0; j < 2; j++) acc[i][j] = (f32x4){0,0,0,0};

  for (int kb = 0; kb < 8; kb++){
    int k0 = kb * 64;
    __syncthreads();
    #pragma unroll
    for (int c = 0; c < 4; c++){
      int e = c * 2048 + tid * 8;
      int row = e >> 6, k = e & 63;
      bf16x8 v = *(const bf16x8*)(A + (long)(m0 + row) * INNER_ + k0 + k);
      *(bf16x8*)(As + (row << 7) + ((k << 1) ^ ((row & 7) << 4))) = v;
    }
    #pragma unroll
    for (int c = 0; c < 2; c++){
      int e = c * 2048 + tid * 8;
      int row = e >> 6, k = e & 63;
      bf16x8 v = *(const bf16x8*)(Wot + (long)(n0 + row) * INNER_ + k0 + k);
      *(bf16x8*)(Bs + (row << 7) + ((k << 1) ^ ((row & 7) << 4))) = v;
    }
    __syncthreads();
    #pragma unroll
    for (int kc = 0; kc < 2; kc++){
      int kk = kc * 32 + cg * 8;
      bf16x8 af[4], bfr[2];
      #pragma unroll
      for (int mt = 0; mt < 4; mt++){
        int row = wr * 64 + mt * 16 + cl;
        af[mt] = *(const bf16x8*)(As + (row << 7) + ((kk << 1) ^ ((row & 7) << 4)));
      }
      #pragma unroll
      for (int nt = 0; nt < 2; nt++){
        int row = wc * 32 + nt * 16 + cl;
        bfr[nt] = *(const bf16x8*)(Bs + (row << 7) + ((kk << 1) ^ ((row & 7) << 4)));
      }
      #pragma unroll
      for (int mt = 0; mt < 4; mt++)
        #pragma unroll
        for (int nt = 0; nt < 2; nt++)
          acc[mt][nt] = mfma16(af[mt], bfr[nt], acc[mt][nt]);
    }
  }
  #pragma unroll
  for (int mt = 0; mt < 4; mt++)
    #pragma unroll
    for (int nt = 0; nt < 2; nt++){
      int row = m0 + wr * 64 + mt * 16 + cg * 4;
      int col = n0 + wc * 32 + nt * 16 + cl;
      float bias = bo[col];
      #pragma unroll
      for (int r = 0; r < 4; r++)
        out[(long)(row + r) * C_ + col] = acc[mt][nt][r] + bias;
    }
}

extern "C" void kernel_launch(void* const* d_in, const int* in_sizes, int n_in,
                              void* d_out, int out_size, void* d_ws, size_t ws_size,
                              hipStream_t stream)
{
  const float* x    = (const float*)d_in[0];
  const float* ctx  = (const float*)d_in[1];
  const void*  mask = d_in[2];
  const float* Wq   = (const float*)d_in[3];
  const float* Wk   = (const float*)d_in[4];
  const float* Wv   = (const float*)d_in[5];
  const float* Wo   = (const float*)d_in[6];
  const float* bo   = (const float*)d_in[7];
  const float* regt = (const float*)d_in[8];
  float* out = (float*)d_out;

  char* ws = (char*)d_ws;
  size_t off = 0;
  int* flag = (int*)ws;                               off = 256;
  unsigned int* maskp = (unsigned int*)(ws + off);    off += (size_t)16384 * 66 * 4;
  bf16_t* Qw  = (bf16_t*)(ws + off);                  off += (size_t)B_*H_*L1_*D_*2;
  bf16_t* Kw  = (bf16_t*)(ws + off);                  off += (size_t)B_*H_*LKP_*D_*2;
  bf16_t* Vtw = (bf16_t*)(ws + off);                  off += (size_t)B_*H_*D_*LKP_*2;
  bf16_t* Att = (bf16_t*)(ws + off);                  off += (size_t)B_*L1_*INNER_*2;
  bf16_t* Wqt = (bf16_t*)(ws + off);                  off += (size_t)C_*INNER_*2;
  bf16_t* Wkt = (bf16_t*)(ws + off);                  off += (size_t)C_*INNER_*2;
  bf16_t* Wvt = (bf16_t*)(ws + off);                  off += (size_t)C_*INNER_*2;
  bf16_t* Wot = (bf16_t*)(ws + off);                  off += (size_t)C_*INNER_*2;
  (void)ws_size; (void)in_sizes; (void)n_in; (void)out_size;

  k_detect<<<1, 64, 0, stream>>>((const unsigned char*)mask, flag);
  k_transpose<<<dim3(16,16,4), 256, 0, stream>>>(Wq, Wk, Wv, Wo, Wqt, Wkt, Wvt, Wot);
  k_maskcompact<<<4096, 256, 0, stream>>>(mask, flag, maskp);
  k_proj<<<dim3(132,4,3), 256, 0, stream>>>(x, ctx, regt, Wqt, Wkt, Wvt, Qw, Kw, Vtw);
  k_attn<<<dim3(16,64), 256, 0, stream>>>(Qw, Kw, Vtw, maskp, Att);
  k_out<<<dim3(128,5), 256, 0, stream>>>(Att, Wot, bo, out);
}